// Round 1
// baseline (1287.470 us; speedup 1.0000x reference)
//
#include <hip/hip_runtime.h>
#include <hip/hip_bf16.h>

// Problem constants (reference: FEAT=1024, N_TAR=60000, N_MSG=45000)
#define FEAT 1024
#define NTAR 60000
#define NMSG 45000
#define MPAD 60032   // 469 * 128, so GEMM M-tiles need no staging clamp
#define BM 128
#define BN 128
#define BK 32
#define KTILES (FEAT / BK)  // 32

typedef __bf16 bf16_t;
typedef __attribute__((ext_vector_type(8))) __bf16 bf16x8;
typedef __attribute__((ext_vector_type(4))) __bf16 bf16x4;
typedef __attribute__((ext_vector_type(4))) float f32x4;

// ---------------------------------------------------------------------------
// inv maps: inv_o[t] = m such that o_idx[m] == t, else -1 (memset 0xFF first)
__global__ __launch_bounds__(256) void build_inv_kernel(
    const int* __restrict__ o_idx, const int* __restrict__ s_idx,
    int* __restrict__ inv_o, int* __restrict__ inv_s, int n) {
  int i = blockIdx.x * 256 + threadIdx.x;
  if (i < n) {
    inv_o[o_idx[i]] = i;
    inv_s[s_idx[i]] = i;
  }
}

// ---------------------------------------------------------------------------
// weights f32 -> bf16 (both W1 and W2), 4 elems/thread
__global__ __launch_bounds__(256) void convw_kernel(
    const float* __restrict__ w1, const float* __restrict__ w2,
    bf16_t* __restrict__ W1b, bf16_t* __restrict__ W2b) {
  int i = (blockIdx.x * 256 + threadIdx.x) * 4;
  f32x4 v1 = *(const f32x4*)(w1 + i);
  f32x4 v2 = *(const f32x4*)(w2 + i);
  bf16x4 o1, o2;
#pragma unroll
  for (int j = 0; j < 4; ++j) {
    o1[j] = (bf16_t)v1[j];
    o2[j] = (bf16_t)v2[j];
  }
  *(bf16x4*)(W1b + i) = o1;
  *(bf16x4*)(W2b + i) = o2;
}

// ---------------------------------------------------------------------------
// Fused prep: A1 = bf16(0.5*(gather(msg_o) + gather(msg_s))), A2 = bf16(tar).
// One block per row (incl. MPAD zero-pad rows); 256 threads x 4 cols.
__global__ __launch_bounds__(256) void prep_kernel(
    const float* __restrict__ msg_o, const float* __restrict__ msg_s,
    const float* __restrict__ tar,
    const int* __restrict__ inv_o, const int* __restrict__ inv_s,
    bf16_t* __restrict__ A1, bf16_t* __restrict__ A2) {
  const long r = blockIdx.x;
  const int c = threadIdx.x * 4;
  bf16x4 s_out, t_out;
  if (r < NTAR) {
    const int mo = inv_o[r];
    const int ms = inv_s[r];
    f32x4 zed = {0.f, 0.f, 0.f, 0.f};
    f32x4 vo = (mo >= 0) ? *(const f32x4*)(msg_o + (long)mo * FEAT + c) : zed;
    f32x4 vs = (ms >= 0) ? *(const f32x4*)(msg_s + (long)ms * FEAT + c) : zed;
    f32x4 vt = *(const f32x4*)(tar + r * FEAT + c);
#pragma unroll
    for (int j = 0; j < 4; ++j) {
      s_out[j] = (bf16_t)(0.5f * (vo[j] + vs[j]));
      t_out[j] = (bf16_t)vt[j];
    }
  } else {
#pragma unroll
    for (int j = 0; j < 4; ++j) {
      s_out[j] = (bf16_t)0.f;
      t_out[j] = (bf16_t)0.f;
    }
  }
  *(bf16x4*)(A1 + r * FEAT + c) = s_out;
  *(bf16x4*)(A2 + r * FEAT + c) = t_out;
}

// ---------------------------------------------------------------------------
// Fused dual-GEMM: out = sum_f32 + relu(A1@W1^T + b1) + relu(A2@W2^T + b2)
// m97 structure: 128x128 tile, BK=32, 4 waves (2x2) of 64x64, 16x16x32 MFMA.
// LDS chunk-XOR swizzle (chunk ^= (row>>1)&3) applied on the *global source*
// during global_load_lds staging (linear LDS dest) and on the ds_read address
// -> stride-64B ds_read_b128 becomes a free 2-way bank alias.
__global__ __launch_bounds__(256, 2) void gemm_kernel(
    const bf16_t* __restrict__ A1, const bf16_t* __restrict__ A2,
    const bf16_t* __restrict__ W1, const bf16_t* __restrict__ W2,
    const float* __restrict__ b1, const float* __restrict__ b2,
    const float* __restrict__ msg_o, const float* __restrict__ msg_s,
    const int* __restrict__ inv_o, const int* __restrict__ inv_s,
    float* __restrict__ out) {
  __shared__ char lds[32768];  // 2 bufs x (A 8KB + B 8KB)
  const int tid = threadIdx.x;
  const int lane = tid & 63;
  const int wid = tid >> 6;
  const int wm = wid >> 1;   // wave row (0..1)
  const int wn = wid & 1;    // wave col (0..1)
  const int ntile = blockIdx.x;             // 0..7
  const long row0 = (long)blockIdx.y * BM;  // 0..468*128
  const int col0 = ntile * BN;

  auto stage = [&](int buf, const bf16_t* A, const bf16_t* W, int kt) {
    char* ldsA = lds + buf * 16384;
    char* ldsB = ldsA + 8192;
#pragma unroll
    for (int i = 0; i < 2; ++i) {
      const int idx = i * 256 + tid;  // 512 chunks of 16B = 8KB tile
      const int row = idx >> 2;       // 0..127
      const int gc = (idx & 3) ^ ((row >> 1) & 3);  // inverse-swizzled source chunk
      const bf16_t* srcA = A + (row0 + row) * FEAT + kt * BK + gc * 8;
      __builtin_amdgcn_global_load_lds(
          (const __attribute__((address_space(1))) void*)srcA,
          (__attribute__((address_space(3))) void*)(ldsA + idx * 16), 16, 0, 0);
      const bf16_t* srcW = W + (long)(col0 + row) * FEAT + kt * BK + gc * 8;
      __builtin_amdgcn_global_load_lds(
          (const __attribute__((address_space(1))) void*)srcW,
          (__attribute__((address_space(3))) void*)(ldsB + idx * 16), 16, 0, 0);
    }
  };

  f32x4 acc1[4][4] = {};
  f32x4 acc2[4][4] = {};

  auto compute = [&](int buf, f32x4(&acc)[4][4]) {
    const char* ldsA = lds + buf * 16384;
    const char* ldsB = ldsA + 8192;
    const int g = lane >> 4;     // k-group (8 bf16 = 16B chunk)
    const int r16 = lane & 15;
    bf16x8 a[4], b[4];
#pragma unroll
    for (int mi = 0; mi < 4; ++mi) {
      const int row = wm * 64 + mi * 16 + r16;
      const int ch = g ^ ((row >> 1) & 3);
      a[mi] = *(const bf16x8*)(ldsA + row * 64 + ch * 16);
    }
#pragma unroll
    for (int ni = 0; ni < 4; ++ni) {
      const int row = wn * 64 + ni * 16 + r16;
      const int ch = g ^ ((row >> 1) & 3);
      b[ni] = *(const bf16x8*)(ldsB + row * 64 + ch * 16);
    }
#pragma unroll
    for (int mi = 0; mi < 4; ++mi)
#pragma unroll
      for (int ni = 0; ni < 4; ++ni)
        acc[mi][ni] =
            __builtin_amdgcn_mfma_f32_16x16x32_bf16(a[mi], b[ni], acc[mi][ni], 0, 0, 0);
  };

  int cur = 0;
  stage(0, A1, W1, 0);
  // Phase 1: summarized @ W1^T
  for (int kt = 0; kt < KTILES; ++kt) {
    __syncthreads();  // drains vmcnt -> buf `cur` staged; prev reads done
    if (kt + 1 < KTILES) stage(cur ^ 1, A1, W1, kt + 1);
    else stage(cur ^ 1, A2, W2, 0);
    compute(cur, acc1);
    cur ^= 1;
  }
  // Phase 2: tar @ W2^T
  for (int kt = 0; kt < KTILES; ++kt) {
    __syncthreads();
    if (kt + 1 < KTILES) stage(cur ^ 1, A2, W2, kt + 1);
    compute(cur, acc2);
    cur ^= 1;
  }

  // Epilogue: C/D layout col = lane&15, row = (lane>>4)*4 + reg (m89/m91).
  const int cbase = col0 + wn * 64 + (lane & 15);
  float b1v[4], b2v[4];
#pragma unroll
  for (int ni = 0; ni < 4; ++ni) {
    b1v[ni] = b1[cbase + ni * 16];
    b2v[ni] = b2[cbase + ni * 16];
  }
  const long rb = row0 + wm * 64 + ((lane >> 4) * 4);
#pragma unroll
  for (int mi = 0; mi < 4; ++mi) {
#pragma unroll
    for (int r = 0; r < 4; ++r) {
      const long row = rb + mi * 16 + r;
      if (row < NTAR) {
        const int mo = inv_o[row];
        const int ms = inv_s[row];
#pragma unroll
        for (int ni = 0; ni < 4; ++ni) {
          const int col = cbase + ni * 16;
          // exact f32 summarized term via re-gather (avoids bf16 round-off)
          float s = 0.f;
          if (mo >= 0) s += 0.5f * msg_o[(long)mo * FEAT + col];
          if (ms >= 0) s += 0.5f * msg_s[(long)ms * FEAT + col];
          float h1 = fmaxf(acc1[mi][ni][r] + b1v[ni], 0.f);
          float h2 = fmaxf(acc2[mi][ni][r] + b2v[ni], 0.f);
          out[row * FEAT + col] = s + h1 + h2;
        }
      }
    }
  }
}

// ---------------------------------------------------------------------------
extern "C" void kernel_launch(void* const* d_in, const int* in_sizes, int n_in,
                              void* d_out, int out_size, void* d_ws, size_t ws_size,
                              hipStream_t stream) {
  const float* msg_o = (const float*)d_in[0];
  const float* msg_s = (const float*)d_in[1];
  const int* o_idx = (const int*)d_in[2];
  const int* s_idx = (const int*)d_in[3];
  const float* tar = (const float*)d_in[4];
  const float* w1 = (const float*)d_in[5];
  const float* b1 = (const float*)d_in[6];
  const float* w2 = (const float*)d_in[7];
  const float* b2 = (const float*)d_in[8];
  float* out = (float*)d_out;

  // ws layout (~250.6 MB total)
  char* ws = (char*)d_ws;
  bf16_t* A1 = (bf16_t*)ws;                                      // MPAD x FEAT bf16
  bf16_t* A2 = (bf16_t*)(ws + (size_t)MPAD * FEAT * 2);          // MPAD x FEAT bf16
  bf16_t* W1b = (bf16_t*)(ws + (size_t)MPAD * FEAT * 4);         // FEAT x FEAT bf16
  bf16_t* W2b = (bf16_t*)(ws + (size_t)MPAD * FEAT * 4 + (size_t)FEAT * FEAT * 2);
  int* inv_o = (int*)(ws + (size_t)MPAD * FEAT * 4 + (size_t)FEAT * FEAT * 4);
  int* inv_s = inv_o + MPAD;

  hipMemsetAsync(inv_o, 0xFF, (size_t)MPAD * 2 * sizeof(int), stream);
  build_inv_kernel<<<(NMSG + 255) / 256, 256, 0, stream>>>(o_idx, s_idx, inv_o,
                                                           inv_s, NMSG);
  convw_kernel<<<(FEAT * FEAT / 4) / 256, 256, 0, stream>>>(w1, w2, W1b, W2b);
  prep_kernel<<<MPAD, 256, 0, stream>>>(msg_o, msg_s, tar, inv_o, inv_s, A1, A2);
  gemm_kernel<<<dim3(FEAT / BN, MPAD / BM), 256, 0, stream>>>(
      A1, A2, W1b, W2b, b1, b2, msg_o, msg_s, inv_o, inv_s, out);
}